// Round 4
// baseline (173.326 us; speedup 1.0000x reference)
//
#include <hip/hip_runtime.h>

#define MTOT 16384        // 8*2048 tokens
#define NFEAT 512         // out features
#define KTOT 4608         // 512 inputs * 9 segments

typedef float f32x4 __attribute__((ext_vector_type(4)));
typedef short s16x8 __attribute__((ext_vector_type(8)));

__device__ __forceinline__ int div9(int c) { return (c * 7282) >> 16; }  // exact for 0 <= c < 32768

#define GLDS(GP, LP) __builtin_amdgcn_global_load_lds( \
    (const __attribute__((address_space(1))) void*)(GP), \
    (__attribute__((address_space(3))) void*)(LP), 16, 0, 0)

// decode 8-bit one-hot mask -> 8 bf16 one-hot fragment (~14 VALU)
// e = bit-spread of 4 mask bits into bytes; v_perm expands bytes->halfword lanes; *0x3F80 scales.
__device__ __forceinline__ s16x8 decode_mask(unsigned msk) {
  unsigned e0 = (msk & 15u) * 0x00204081u & 0x01010101u;   // bytes = bits 0..3
  unsigned e1 = (msk >> 4)  * 0x00204081u & 0x01010101u;   // bytes = bits 4..7
  unsigned d0 = __builtin_amdgcn_perm(e0, e0, 0x0C010C00u) * 0x3F80u;  // shorts {bit0,bit1}
  unsigned d1 = __builtin_amdgcn_perm(e0, e0, 0x0C030C02u) * 0x3F80u;  // shorts {bit2,bit3}
  unsigned d2 = __builtin_amdgcn_perm(e1, e1, 0x0C010C00u) * 0x3F80u;  // shorts {bit4,bit5}
  unsigned d3 = __builtin_amdgcn_perm(e1, e1, 0x0C030C02u) * 0x3F80u;  // shorts {bit6,bit7}
  union { unsigned d[4]; s16x8 v; } u;
  u.d[0] = d0; u.d[1] = d1; u.d[2] = d2; u.d[3] = d3;
  return u.v;
}

// ---------------- fused prep: bx<2048 -> build_b, else build_codes (mask bytes) ----------------
__global__ __launch_bounds__(256) void prep(const float* __restrict__ x,
                                            const float* __restrict__ coeffs,
                                            unsigned char* __restrict__ codeT,
                                            unsigned short* __restrict__ Bmat) {
  __shared__ unsigned char segt[64][68];
  const int bx = blockIdx.x;
  const int tid = threadIdx.x;
  if (bx < 2048) {
    // ---- build_b: coeffs -> Bmat[i][k] bf16, k = j*9+s ----
    const int i = bx >> 2, q = bx & 3;
    const float* cb = coeffs + (size_t)i * 6144;
#pragma unroll
    for (int p = 0; p < 5; ++p) {
      int kl = p * 256 + tid;
      if (kl < 1152) {
        int k = q * 1152 + kl;
        int j = div9(k), s = k - j * 9;
        float v = cb[j * 12 + s] + cb[j * 12 + s + 1] + cb[j * 12 + s + 2];
        unsigned u = __float_as_uint(v);
        unsigned rn = (u + 0x7FFFu + ((u >> 16) & 1u)) >> 16;  // RNE f32->bf16
        Bmat[(size_t)i * KTOT + k] = (unsigned short)rn;
      }
    }
  } else {
    // ---- build_codes: x -> codeT[g][m] one-hot masks, 64 tokens x 64 inputs per block ----
    const int bb = bx - 2048;
    const int mt = bb >> 3;   // 0..255
    const int jt = bb & 7;    // 0..7
    const int m0 = mt * 64;
    const float4* x4 = (const float4*)x;
    const float T1 = (float)(1.0/9.0), T2 = (float)(2.0/9.0), T3 = (float)(3.0/9.0),
                T4 = (float)(4.0/9.0), T5 = (float)(5.0/9.0), T6 = (float)(6.0/9.0),
                T7 = (float)(7.0/9.0), T8 = (float)(8.0/9.0);
#pragma unroll
    for (int it = 0; it < 4; ++it) {
      int f = it * 256 + tid;
      int m = f >> 4, jq = f & 15;
      float4 v = x4[(size_t)(m0 + m) * 128 + jt * 16 + jq];
      uchar4 sv;
      { float xv = v.x; sv.x = (unsigned char)((xv>=T1)+(xv>=T2)+(xv>=T3)+(xv>=T4)+(xv>=T5)+(xv>=T6)+(xv>=T7)+(xv>=T8)); }
      { float xv = v.y; sv.y = (unsigned char)((xv>=T1)+(xv>=T2)+(xv>=T3)+(xv>=T4)+(xv>=T5)+(xv>=T6)+(xv>=T7)+(xv>=T8)); }
      { float xv = v.z; sv.z = (unsigned char)((xv>=T1)+(xv>=T2)+(xv>=T3)+(xv>=T4)+(xv>=T5)+(xv>=T6)+(xv>=T7)+(xv>=T8)); }
      { float xv = v.w; sv.w = (unsigned char)((xv>=T1)+(xv>=T2)+(xv>=T3)+(xv>=T4)+(xv>=T5)+(xv>=T6)+(xv>=T7)+(xv>=T8)); }
      *(uchar4*)&segt[m][jq * 4] = sv;
    }
    __syncthreads();
#pragma unroll
    for (int p = 0; p < 5; ++p) {
      int u = p * 256 + tid;
      if (u < 1152) {
        int gl = u >> 4, mq = u & 15;
        int c0 = jt * 576 + gl * 8;
        int j0 = div9(c0), j1 = div9(c0 + 7);
        int j0l = j0 - jt * 64, j1l = j1 - jt * 64;
        uchar4 ob;
        unsigned char* pb = (unsigned char*)&ob;
#pragma unroll
        for (int c = 0; c < 4; ++c) {
          int m = mq * 4 + c;
          int s0 = segt[m][j0l];
          int pos0 = j0 * 9 + s0 - c0;
          unsigned code = (pos0 >= 0 && pos0 < 8) ? (1u << pos0) : 0u;
          if (j1 != j0) {
            int s1 = segt[m][j1l];
            int pos1 = j1 * 9 + s1 - c0;
            if (pos1 < 8) code |= (1u << pos1);
          }
          pb[c] = (unsigned char)code;
        }
        *(uchar4*)(codeT + (size_t)(jt * 72 + gl) * MTOT + m0 + mq * 4) = ob;
      }
    }
  }
}

// ---------------- main: one-hot bf16 MFMA GEMM, 128x64 tile, 4 blocks/CU ----------------
__global__ __launch_bounds__(256, 4) void kan_gemm(const unsigned char* __restrict__ codeT,
                                                   const unsigned short* __restrict__ Bmat,
                                                   float* __restrict__ out) {
  __shared__ __align__(16) short Blds[2][8 * 512];  // 2 x 8KB, fragment-major (8 slots)
  const int tid = threadIdx.x;
  const int lane = tid & 63;
  const int wid = tid >> 6;   // 4 waves, stacked in m
  const int lm = lane & 15;
  const int lq = lane >> 4;
  const int bx = blockIdx.x;
  const int nt = bx & 7;      // XCD-pinned B slice (64 cols, 590 KB -> L2 resident)
  const int mt = bx >> 3;     // 0..127
  const int m0 = mt * 128, n0 = nt * 64;

  // B staging: wave wid owns slots {wid*2 (ks0), wid*2+1 (ks1)}: row n0+wid*16+lm, k = lq*8 (+32)
  const unsigned short* gB = Bmat + (size_t)(n0 + wid * 16 + lm) * KTOT + lq * 8;
  // codes: frag f = ms*2+ks; row = m0 + wid*32 + ms*16 + lm; group = kt*8 + ks*4 + lq
  const unsigned char* gC0 = codeT + (size_t)lq * MTOT + m0 + wid * 32 + lm;        // ks=0
  const unsigned char* gC1 = codeT + (size_t)(4 + lq) * MTOT + m0 + wid * 32 + lm;  // ks=1

  f32x4 acc[2][4] = {};
  s16x8 afA[4], afB[4];
  unsigned char cr[4];

#define LOAD_CR() do { \
    cr[0] = gC0[0]; cr[1] = gC1[0]; cr[2] = gC0[16]; cr[3] = gC1[16]; \
    gC0 += (size_t)8 * MTOT; gC1 += (size_t)8 * MTOT; } while (0)

#define ISSUE_B(buf) do { \
    short* base = &Blds[buf][0] + wid * 1024; \
    GLDS(gB,      base);        \
    GLDS(gB + 32, base + 512);  \
    gB += 64; } while (0)

#define COMPUTE(AF, buf) do { \
    _Pragma("unroll") \
    for (int ks = 0; ks < 2; ++ks) { \
      s16x8 bf[4]; \
      _Pragma("unroll") \
      for (int ns = 0; ns < 4; ++ns) \
        bf[ns] = *(const s16x8*)&Blds[buf][(ns * 2 + ks) * 512 + lane * 8]; \
      _Pragma("unroll") \
      for (int ms = 0; ms < 2; ++ms) \
        _Pragma("unroll") \
        for (int ns = 0; ns < 4; ++ns) \
          acc[ms][ns] = __builtin_amdgcn_mfma_f32_16x16x32_bf16(AF[ms * 2 + ks], bf[ns], acc[ms][ns], 0, 0, 0); \
    } } while (0)

  // prologue: stage kt=0, decode kt=0 frags, prefetch kt=1 codes
  LOAD_CR();
  ISSUE_B(0);
#pragma unroll
  for (int f = 0; f < 4; ++f) afA[f] = decode_mask(cr[f]);
  LOAD_CR();
  __syncthreads();  // Blds[0] ready

#pragma unroll 1
  for (int kt = 0; kt < 72; kt += 2) {
    // phase A: compute kt; prefetch B(kt+1); decode codes(kt+1)->afB; load codes(kt+2)
    ISSUE_B(1);
#pragma unroll
    for (int f = 0; f < 4; ++f) afB[f] = decode_mask(cr[f]);
    if (kt < 70) LOAD_CR();
    COMPUTE(afA, 0);
    __syncthreads();
    // phase B: compute kt+1; prefetch B(kt+2); decode codes(kt+2)->afA; load codes(kt+3)
    if (kt < 70) {
      ISSUE_B(0);
#pragma unroll
      for (int f = 0; f < 4; ++f) afA[f] = decode_mask(cr[f]);
      LOAD_CR();
    }
    COMPUTE(afB, 1);
    __syncthreads();
  }

  // epilogue: C/D layout col=lane&15, row=quad*4+reg (verified R1-R3)
#pragma unroll
  for (int ms = 0; ms < 2; ++ms) {
#pragma unroll
    for (int ns = 0; ns < 4; ++ns) {
      int tok = m0 + wid * 32 + ms * 16 + lq * 4;
      int col = n0 + ns * 16 + lm;
      float* op = out + (size_t)tok * NFEAT + col;
#pragma unroll
      for (int rg = 0; rg < 4; ++rg) op[(size_t)rg * NFEAT] = acc[ms][ns][rg];
    }
  }
}

extern "C" void kernel_launch(void* const* d_in, const int* in_sizes, int n_in,
                              void* d_out, int out_size, void* d_ws, size_t ws_size,
                              hipStream_t stream) {
  const float* x = (const float*)d_in[0];        // [16384, 512] f32
  const float* coeffs = (const float*)d_in[1];   // [512, 512, 12] f32
  float* out = (float*)d_out;                    // [16384, 512] f32
  unsigned char* codeT = (unsigned char*)d_ws;                                  // 576*16384 = 9.44 MB
  unsigned short* Bmat = (unsigned short*)((char*)d_ws + (size_t)576 * MTOT);   // 512*4608*2 = 4.72 MB

  prep<<<dim3(4096), dim3(256), 0, stream>>>(x, coeffs, codeT, Bmat);
  kan_gemm<<<dim3(1024), dim3(256), 0, stream>>>(codeT, Bmat, out);
}